// Round 3
// baseline (9512.630 us; speedup 1.0000x reference)
//
#include <hip/hip_runtime.h>
#include <math.h>

// Sinkhorn OT layer, B=8192, C=256, L=100, LAMBD=1.
//
// Reformulation: with U = log_u - ||x_i||^2, V = log_v - ||y_j||^2 and
// G[i][j] = 2*dot(x_i, y_j):
//   U[i] = -LSE_j(G[i][j] + V[j])
//   V[j] = -LSE_i(G[i][j] + U[i])
// init V[j] = -||y_j||^2 (log_v = 0). Final: out[i] = y[argmax_j(G[i][j]+V[j])].
// ||x||^2 never needed (row-constant shifts cancel in duals and argmax).
//
// Memory plan (ws_size assumed >= 256 MiB, and G is EXACTLY 256 MiB):
//   d_ws : G only (8192*8192*4 = 268435456 B)
//   d_out: scratch during iterations (8 MiB total available):
//          U  (8192 f) | V (8192 f) | pm (32*8192 f) | ps (32*8192 f)  ~2.07 MiB
//   Final phase: fold V into G in place (G[i][j] += V[j]), THEN argmax+gather
//   writes all of d_out. So d_out scratch is never read after output writes
//   begin -> no inter-block hazard.

#define B 8192
#define C 256
#define LITERS 100
#define CHUNKS 32
#define RPC (B / CHUNKS)   // 256 rows per chunk

// ---------------- init: V[j] = -||y_j||^2 ----------------
__global__ __launch_bounds__(256) void init_V(const float* __restrict__ y,
                                              float* __restrict__ V) {
    int wave = threadIdx.x >> 6;
    int lane = threadIdx.x & 63;
    int row = blockIdx.x * 4 + wave;
    const float4* yr = (const float4*)(y + (size_t)row * C);
    float4 v = yr[lane];                       // 64 lanes * 4 = 256 elems
    float s = v.x * v.x + v.y * v.y + v.z * v.z + v.w * v.w;
    #pragma unroll
    for (int off = 32; off; off >>= 1) s += __shfl_down(s, off, 64);
    if (lane == 0) V[row] = -s;
}

// ---------------- GEMM: G = 2 * x @ y^T (f32, 64x64 tiles) ----------------
#define GT 64
#define GKT 64
#define GPAD 4   // row stride 68 floats = 272 B = 17*16 B, keeps float4 alignment

__global__ __launch_bounds__(256) void gemm_G(const float* __restrict__ x,
                                              const float* __restrict__ y,
                                              float* __restrict__ G) {
    __shared__ float As[GKT][GT + GPAD];   // [k][i]
    __shared__ float Bs[GKT][GT + GPAD];   // [k][j]
    int bi = blockIdx.y * GT;
    int bj = blockIdx.x * GT;
    int t = threadIdx.x;
    int tx = t & 15, ty = t >> 4;
    float acc[4][4] = {};
    for (int kk = 0; kk < C; kk += GKT) {
        #pragma unroll
        for (int l = 0; l < 4; ++l) {
            int e = (t + l * 256) * 4;     // element offset in 64x64 tile
            int r = e >> 6;                // tile row 0..63
            int c = e & 63;                // tile k   0..63 (step 4)
            float4 va = *(const float4*)(x + (size_t)(bi + r) * C + kk + c);
            As[c + 0][r] = va.x; As[c + 1][r] = va.y;
            As[c + 2][r] = va.z; As[c + 3][r] = va.w;
            float4 vb = *(const float4*)(y + (size_t)(bj + r) * C + kk + c);
            Bs[c + 0][r] = vb.x; Bs[c + 1][r] = vb.y;
            Bs[c + 2][r] = vb.z; Bs[c + 3][r] = vb.w;
        }
        __syncthreads();
        #pragma unroll 8
        for (int k = 0; k < GKT; ++k) {
            float4 a = *(const float4*)&As[k][ty * 4];
            float4 b = *(const float4*)&Bs[k][tx * 4];
            float av[4] = {a.x, a.y, a.z, a.w};
            float bv[4] = {b.x, b.y, b.z, b.w};
            #pragma unroll
            for (int ii = 0; ii < 4; ++ii)
                #pragma unroll
                for (int jj = 0; jj < 4; ++jj)
                    acc[ii][jj] = fmaf(av[ii], bv[jj], acc[ii][jj]);
        }
        __syncthreads();
    }
    #pragma unroll
    for (int ii = 0; ii < 4; ++ii) {
        int gi = bi + ty * 4 + ii;
        float4 o;
        o.x = 2.0f * acc[ii][0]; o.y = 2.0f * acc[ii][1];
        o.z = 2.0f * acc[ii][2]; o.w = 2.0f * acc[ii][3];
        *(float4*)(G + (size_t)gi * B + bj + tx * 4) = o;
    }
}

// ---------------- row pass: U[i] = -LSE_j(G[i][j] + V[j]) ----------------
__global__ __launch_bounds__(256) void row_lse(const float* __restrict__ G,
                                               const float* __restrict__ V,
                                               float* __restrict__ U) {
    int i = blockIdx.x;
    int t = threadIdx.x;
    const float4* g = (const float4*)(G + (size_t)i * B);
    const float4* v4 = (const float4*)V;
    float m = -INFINITY, s = 0.0f;
    #pragma unroll
    for (int it = 0; it < B / (256 * 4); ++it) {   // 8 iterations
        int idx = it * 256 + t;
        float4 gv = g[idx];
        float4 vv = v4[idx];
        float vals[4] = {gv.x + vv.x, gv.y + vv.y, gv.z + vv.z, gv.w + vv.w};
        #pragma unroll
        for (int k = 0; k < 4; ++k) {
            float val = vals[k];
            float m2 = fmaxf(m, val);
            s = s * __expf(m - m2) + __expf(val - m2);
            m = m2;
        }
    }
    __shared__ float sm[256], ss[256];
    sm[t] = m; ss[t] = s;
    __syncthreads();
    #pragma unroll
    for (int off = 128; off; off >>= 1) {
        if (t < off) {
            float mo = sm[t + off], so = ss[t + off];
            float m1 = sm[t],       s1 = ss[t];
            float m2 = fmaxf(m1, mo);
            ss[t] = s1 * __expf(m1 - m2) + so * __expf(mo - m2);
            sm[t] = m2;
        }
        __syncthreads();
    }
    if (t == 0) U[i] = -(sm[0] + logf(ss[0]));
}

// ------- column pass (partials): per (chunk, j): online LSE over 256 rows -------
__global__ __launch_bounds__(256) void col_lse_partial(const float* __restrict__ G,
                                                       const float* __restrict__ U,
                                                       float* __restrict__ pm,
                                                       float* __restrict__ ps) {
    int j = blockIdx.x * 256 + threadIdx.x;
    int chunk = blockIdx.y;
    int i0 = chunk * RPC;
    __shared__ float Us[RPC];
    Us[threadIdx.x] = U[i0 + threadIdx.x];
    __syncthreads();
    float m = -INFINITY, s = 0.0f;
    const float* gp = G + (size_t)i0 * B + j;
    #pragma unroll 8
    for (int r = 0; r < RPC; ++r) {
        float val = gp[(size_t)r * B] + Us[r];
        float m2 = fmaxf(m, val);
        s = s * __expf(m - m2) + __expf(val - m2);
        m = m2;
    }
    pm[chunk * B + j] = m;
    ps[chunk * B + j] = s;
}

// ---------------- column combine: V[j] = -(LSE of 32 partials) ----------------
__global__ __launch_bounds__(256) void col_combine(const float* __restrict__ pm,
                                                   const float* __restrict__ ps,
                                                   float* __restrict__ V) {
    int j = blockIdx.x * 256 + threadIdx.x;
    float m = -INFINITY, s = 0.0f;
    #pragma unroll
    for (int c = 0; c < CHUNKS; ++c) {
        float mc = pm[c * B + j], sc = ps[c * B + j];
        float m2 = fmaxf(m, mc);
        s = s * __expf(m - m2) + sc * __expf(mc - m2);
        m = m2;
    }
    V[j] = -(m + logf(s));
}

// ---------------- fold: G[i][j] += V[j] (in place) ----------------
// After this, argmax needs only G -> final kernel is the sole toucher of d_out.
__global__ __launch_bounds__(256) void fold_V(float* __restrict__ G,
                                              const float* __restrict__ V) {
    size_t idx = (size_t)blockIdx.x * 256 + threadIdx.x;   // float4 index
    int j4 = (int)(idx & (B / 4 - 1));                     // 2048 float4 per row
    float4 g = ((const float4*)G)[idx];
    float4 v = ((const float4*)V)[j4];
    g.x += v.x; g.y += v.y; g.z += v.z; g.w += v.w;
    ((float4*)G)[idx] = g;
}

// ---------------- argmax + gather: out[i] = y[argmax_j G[i][j]] ----------------
__global__ __launch_bounds__(256) void argmax_out(const float* __restrict__ G,
                                                  const float* __restrict__ y,
                                                  float* __restrict__ out) {
    int i = blockIdx.x;
    int t = threadIdx.x;
    const float* g = G + (size_t)i * B;
    float best = -INFINITY;
    int bj = B;
    #pragma unroll
    for (int it = 0; it < B / 256; ++it) {
        int j = it * 256 + t;
        float val = g[j];
        if (val > best) { best = val; bj = j; }   // strict > keeps earliest j
    }
    __shared__ float bm[256];
    __shared__ int   bidx[256];
    bm[t] = best; bidx[t] = bj;
    __syncthreads();
    #pragma unroll
    for (int off = 128; off; off >>= 1) {
        if (t < off) {
            float om = bm[t + off]; int oj = bidx[t + off];
            if (om > bm[t] || (om == bm[t] && oj < bidx[t])) { bm[t] = om; bidx[t] = oj; }
        }
        __syncthreads();
    }
    int jstar = bidx[0];
    out[(size_t)i * C + t] = y[(size_t)jstar * C + t];
}

extern "C" void kernel_launch(void* const* d_in, const int* in_sizes, int n_in,
                              void* d_out, int out_size, void* d_ws, size_t ws_size,
                              hipStream_t stream) {
    const float* x = (const float*)d_in[0];
    const float* y = (const float*)d_in[1];
    float* out = (float*)d_out;

    // d_ws: G only (exactly 256 MiB).
    float* G = (float*)d_ws;
    // d_out doubles as iteration scratch (~2.07 MiB of 8 MiB); it is fully
    // overwritten by argmax_out at the end, after all scratch reads are done.
    float* U  = out;                 // 8192 f
    float* V  = U + B;               // 8192 f
    float* pm = V + B;               // 32*8192 f
    float* ps = pm + CHUNKS * B;     // 32*8192 f

    init_V<<<B / 4, 256, 0, stream>>>(y, V);
    gemm_G<<<dim3(B / GT, B / GT), 256, 0, stream>>>(x, y, G);
    for (int l = 0; l < LITERS; ++l) {
        row_lse<<<B, 256, 0, stream>>>(G, V, U);
        col_lse_partial<<<dim3(B / 256, CHUNKS), 256, 0, stream>>>(G, U, pm, ps);
        col_combine<<<B / 256, 256, 0, stream>>>(pm, ps, V);
    }
    fold_V<<<(B / 4) * B / 256, 256, 0, stream>>>(G, V);
    argmax_out<<<B, 256, 0, stream>>>(G, y, out);
}